// Round 1
// baseline (440.459 us; speedup 1.0000x reference)
//
#include <hip/hip_runtime.h>

// out[b,n,k] = |x[b,n,k]| * (1 - w[b,k]*C/(C-1)) + w[b,k] * S[b,n]/(C-1)
// where S[b,n] = sum_c |x[b,n,c]|.  B=64, N=1024, C=1000 (fixed by harness).
//
// Structure: one 64-lane wave owns one row (C=1000 floats) entirely in
// registers: 4 float4 per lane (16 floats/lane * 64 lanes = 1024 >= 1000).
// Row sum via 6-step __shfl_xor butterfly -- no LDS, no __syncthreads.
// Each wave processes 8 consecutive rows of the same b, so w[b,:] is loaded
// once per wave (not once per row). Grid = 2048 blocks * 256 threads.

constexpr int B = 64;
constexpr int N = 1024;
constexpr int C = 1000;
constexpr int F4 = C / 4;              // 250 float4 per row
constexpr int ROWS_PER_WAVE = 8;       // 8 | 1024, so b is constant per wave
constexpr int WAVES  = (B * N) / ROWS_PER_WAVE;  // 8192
constexpr int BLOCKS = WAVES / 4;                // 2048 (4 waves per block)

__device__ __forceinline__ float4 absf4(float4 v) {
    return make_float4(fabsf(v.x), fabsf(v.y), fabsf(v.z), fabsf(v.w));
}
__device__ __forceinline__ float hsum4(float4 v) {
    return (v.x + v.y) + (v.z + v.w);
}
__device__ __forceinline__ float4 wf4(float4 a, float4 wv, float Sinv) {
    // o = a + w*(Sinv - a*Cr)  ==  a*(1 - w*C/(C-1)) + w*S/(C-1)
    constexpr float Cr = (float)C / (float)(C - 1);
    float4 o;
    o.x = fmaf(wv.x, fmaf(-a.x, Cr, Sinv), a.x);
    o.y = fmaf(wv.y, fmaf(-a.y, Cr, Sinv), a.y);
    o.z = fmaf(wv.z, fmaf(-a.z, Cr, Sinv), a.z);
    o.w = fmaf(wv.w, fmaf(-a.w, Cr, Sinv), a.w);
    return o;
}

__global__ __launch_bounds__(256) void wf_kernel(
    const float* __restrict__ x,   // [B,N,C]
    const float* __restrict__ w,   // [B,C]
    float* __restrict__ out)       // [B,N,C]
{
    const int tid  = threadIdx.x;
    const int lane = tid & 63;
    const int wv   = (blockIdx.x << 2) + (tid >> 6);   // wave id, 0..8191
    const int row0 = wv * ROWS_PER_WAVE;               // first of 8 rows
    const int b    = row0 >> 10;                       // N = 1024

    // float4 indices within the row (interleaved for coalescing)
    const int i0 = lane;
    const int i1 = lane + 64;
    const int i2 = lane + 128;
    const int i3 = lane + 192;
    const bool v3 = (i3 < F4);     // lanes 0..57 carry the tail quarter

    // load w[b,:] fragments once for all 8 rows
    const float4* wb = reinterpret_cast<const float4*>(w + (long long)b * C);
    const float4 w0 = wb[i0];
    const float4 w1 = wb[i1];
    const float4 w2 = wb[i2];
    const float4 w3 = v3 ? wb[i3] : make_float4(0.f, 0.f, 0.f, 0.f);

    constexpr float inv = 1.0f / (float)(C - 1);

    #pragma unroll 2
    for (int r = 0; r < ROWS_PER_WAVE; ++r) {
        const long long base = (long long)(row0 + r) * C;
        const float4* xr = reinterpret_cast<const float4*>(x + base);

        // 4 loads issued back-to-back: 4 KB of this row in flight per wave
        float4 a0 = xr[i0];
        float4 a1 = xr[i1];
        float4 a2 = xr[i2];
        float4 a3 = v3 ? xr[i3] : make_float4(0.f, 0.f, 0.f, 0.f);

        a0 = absf4(a0); a1 = absf4(a1); a2 = absf4(a2); a3 = absf4(a3);

        // per-lane partial, then 64-lane butterfly (every lane gets S)
        float p = (hsum4(a0) + hsum4(a1)) + (hsum4(a2) + hsum4(a3));
        #pragma unroll
        for (int off = 32; off > 0; off >>= 1)
            p += __shfl_xor(p, off, 64);
        const float Sinv = p * inv;

        float4* orow = reinterpret_cast<float4*>(out + base);
        orow[i0] = wf4(a0, w0, Sinv);
        orow[i1] = wf4(a1, w1, Sinv);
        orow[i2] = wf4(a2, w2, Sinv);
        if (v3) orow[i3] = wf4(a3, w3, Sinv);
    }
}

extern "C" void kernel_launch(void* const* d_in, const int* in_sizes, int n_in,
                              void* d_out, int out_size, void* d_ws, size_t ws_size,
                              hipStream_t stream) {
    const float* x = (const float*)d_in[0];   // residual [B,N,C]
    const float* w = (const float*)d_in[1];   // weight   [B,C]
    float* out = (float*)d_out;               // [B,N,C]
    (void)in_sizes; (void)n_in; (void)d_ws; (void)ws_size; (void)out_size;

    wf_kernel<<<BLOCKS, 256, 0, stream>>>(x, w, out);
}

// Round 2
// 414.257 us; speedup vs baseline: 1.0633x; 1.0633x over previous
//
#include <hip/hip_runtime.h>

// out[b,n,k] = |x[b,n,k]| * (1 - w[b,k]*C/(C-1)) + w[b,k] * S[b,n]/(C-1)
// where S[b,n] = sum_c |x[b,n,c]|.  B=64, N=1024, C=1000 (fixed by harness).
//
// Structure: one 256-thread block per row (proven fastest — massive TLP keeps
// HBM saturated; the wave-per-row variant regressed 87->114 us).
// Reduce: 64-lane shfl_down + ONE barrier; every thread sums the 4 wave
// partials from LDS itself (broadcast reads) — no second barrier, no tid-0
// serial combine.

constexpr int B = 64;
constexpr int N = 1024;
constexpr int C = 1000;

__global__ __launch_bounds__(256) void wf_kernel(
    const float* __restrict__ x,   // [B,N,C]
    const float* __restrict__ w,   // [B,C]
    float* __restrict__ out)       // [B,N,C]
{
    const int row = blockIdx.x;            // b*N + n
    const int b   = row >> 10;             // N = 1024
    const long long base = (long long)row * C;
    const int tid = threadIdx.x;
    const int c4  = tid * 4;

    __shared__ float s_wave[4];

    float ax = 0.f, ay = 0.f, az = 0.f, aw = 0.f;
    float wx = 0.f, wy = 0.f, wz = 0.f, ww = 0.f;
    if (c4 < C) {
        float4 xv = *reinterpret_cast<const float4*>(x + base + c4);
        float4 wv = *reinterpret_cast<const float4*>(w + (long long)b * C + c4);
        ax = fabsf(xv.x); ay = fabsf(xv.y); az = fabsf(xv.z); aw = fabsf(xv.w);
        wx = wv.x; wy = wv.y; wz = wv.z; ww = wv.w;
    }

    // wave-level reduce (64 lanes), lane 0 holds the wave partial
    float partial = (ax + ay) + (az + aw);
    #pragma unroll
    for (int off = 32; off > 0; off >>= 1)
        partial += __shfl_down(partial, off, 64);
    const int wave = tid >> 6;
    const int lane = tid & 63;
    if (lane == 0) s_wave[wave] = partial;
    __syncthreads();
    // every thread combines the 4 partials itself (LDS broadcast reads)
    const float S = (s_wave[0] + s_wave[1]) + (s_wave[2] + s_wave[3]);

    if (c4 < C) {
        constexpr float inv = 1.0f / (float)(C - 1);
        constexpr float Cr  = (float)C / (float)(C - 1);   // 1 + inv
        const float Sinv = S * inv;
        // o = a + w*(Sinv - a*Cr)  ==  a*(1 - w*C/(C-1)) + w*S/(C-1)
        float4 o;
        o.x = fmaf(wx, fmaf(-ax, Cr, Sinv), ax);
        o.y = fmaf(wy, fmaf(-ay, Cr, Sinv), ay);
        o.z = fmaf(wz, fmaf(-az, Cr, Sinv), az);
        o.w = fmaf(ww, fmaf(-aw, Cr, Sinv), aw);
        *reinterpret_cast<float4*>(out + base + c4) = o;
    }
}

extern "C" void kernel_launch(void* const* d_in, const int* in_sizes, int n_in,
                              void* d_out, int out_size, void* d_ws, size_t ws_size,
                              hipStream_t stream) {
    const float* x = (const float*)d_in[0];   // residual [B,N,C]
    const float* w = (const float*)d_in[1];   // weight   [B,C]
    float* out = (float*)d_out;               // [B,N,C]
    (void)in_sizes; (void)n_in; (void)d_ws; (void)ws_size; (void)out_size;

    wf_kernel<<<B * N, 256, 0, stream>>>(x, w, out);
}